// Round 10
// baseline (538.633 us; speedup 1.0000x reference)
//
#include <hip/hip_runtime.h>
#include <math.h>

#define N_NODES 20000
#define N_EDGES 320000
#define N_GRAPHS 32
#define CDIM 256
#define IN_DIMV 739
#define KPAD_DENSE 768
#define ED_DIM 518
#define NLAYERS 4
#define LN_EPS 1e-5f
#define SCAN_BLOCKS ((N_NODES + 255) / 256)  // 79

typedef _Float16 f16x8 __attribute__((ext_vector_type(8)));
typedef _Float16 f16x4 __attribute__((ext_vector_type(4)));
typedef float f32x4 __attribute__((ext_vector_type(4)));

__device__ __forceinline__ float gelu_exact(float x) {
    return 0.5f * x * (1.f + erff(x * 0.7071067811865475f));
}

__device__ __forceinline__ void gll16(const void* g, void* l) {
    __builtin_amdgcn_global_load_lds((const __attribute__((address_space(1))) void*)g,
                                     (__attribute__((address_space(3))) void*)l, 16, 0, 0);
}

// ---- merged setup: zero deg | cw/SgSb | dense W | sq W | zero sdot |
//      convert x fp32->fp16 padded ----
__global__ __launch_bounds__(256)
void prep_all(const float* __restrict__ ln1_g, const float* __restrict__ ln1_b,
              const float* __restrict__ w1_w, float* __restrict__ cw,
              float* __restrict__ SgSb,
              const float* __restrict__ dense_w, _Float16* __restrict__ wt_dense,
              const float* __restrict__ d1_w, const float* __restrict__ d2_w,
              _Float16* __restrict__ wt_sq, int* __restrict__ deg,
              float* __restrict__ sdot,
              const float* __restrict__ x, _Float16* __restrict__ xh) {
    __shared__ float smem[2048 + 64];
    int b = blockIdx.x, tid = threadIdx.x;
    if (b < 79) {
        int i = b * 256 + tid;
        if (i < N_NODES) deg[i] = 0;
    } else if (b < 83) {
        int l = b - 79;
        float sg[4] = {0, 0, 0, 0}, sb[4] = {0, 0, 0, 0};
        for (int i = tid; i < ED_DIM; i += 256) {
            float g = ln1_g[l * ED_DIM + i];
            float bb = ln1_b[l * ED_DIM + i];
            float4 w = *(const float4*)&w1_w[(size_t)(l * ED_DIM + i) * 4];
            float4 c = make_float4(g * w.x, g * w.y, g * w.z, g * w.w);
            *(float4*)&cw[(size_t)(l * ED_DIM + i) * 4] = c;
            sg[0] += c.x; sg[1] += c.y; sg[2] += c.z; sg[3] += c.w;
            sb[0] += bb * w.x; sb[1] += bb * w.y; sb[2] += bb * w.z; sb[3] += bb * w.w;
        }
        for (int c = 0; c < 4; c++) { smem[tid * 8 + c] = sg[c]; smem[tid * 8 + 4 + c] = sb[c]; }
        __syncthreads();
        for (int s = 128; s > 0; s >>= 1) {
            if (tid < s)
                for (int c = 0; c < 8; c++) smem[tid * 8 + c] += smem[(tid + s) * 8 + c];
            __syncthreads();
        }
        if (tid < 8) SgSb[l * 8 + tid] = smem[tid];
    } else if (b < 275) {
        int q = b - 83;
        int kt = q >> 3, nt = q & 7;
        int i = tid >> 5, j = tid & 31;
        float* T = smem;  // [32][33]
#pragma unroll
        for (int ii = 0; ii < 4; ii++) {
            int k = kt * 32 + i + ii * 8;
            T[(i + ii * 8) * 33 + j] = (k < IN_DIMV) ? dense_w[(size_t)k * 256 + nt * 32 + j] : 0.f;
        }
        __syncthreads();
#pragma unroll
        for (int ii = 0; ii < 4; ii++) {
            int n = nt * 32 + i + ii * 8;
            wt_dense[(size_t)n * KPAD_DENSE + kt * 32 + j] = (_Float16)T[j * 33 + i + ii * 8];
        }
    } else if (b < 787) {
        int q = b - 275;
        int z = q >> 6, kt = (q >> 3) & 7, nt = q & 7;
        const float* W = (z < 4) ? d1_w + (size_t)z * 65536 : d2_w + (size_t)(z - 4) * 65536;
        _Float16* O = wt_sq + (size_t)z * 65536;
        int i = tid >> 5, j = tid & 31;
        float* T = smem;
#pragma unroll
        for (int ii = 0; ii < 4; ii++)
            T[(i + ii * 8) * 33 + j] = W[(size_t)(kt * 32 + i + ii * 8) * 256 + nt * 32 + j];
        __syncthreads();
#pragma unroll
        for (int ii = 0; ii < 4; ii++)
            O[(size_t)(nt * 32 + i + ii * 8) * 256 + kt * 32 + j] = (_Float16)T[j * 33 + i + ii * 8];
    } else if (b < 866) {
        int i = (b - 787) * 256 + tid;
        if (i < N_NODES) sdot[i] = 0.f;
    } else {
        // convert x [N][739] fp32 -> xh [N][768] fp16, zero-padded
        const int cb = b - 866;                 // 2048 blocks
        const int stride = 2048 * 256;
        const int nquads = (N_NODES * IN_DIMV) / 4;
        for (int q = cb * 256 + tid; q < nquads; q += stride) {
            float4 v = ((const float4*)x)[q];
            int base = q * 4;
            float vv[4] = {v.x, v.y, v.z, v.w};
#pragma unroll
            for (int e = 0; e < 4; ++e) {
                int idx = base + e;
                int row = idx / IN_DIMV;
                int col = idx - row * IN_DIMV;
                xh[row * KPAD_DENSE + col] = (_Float16)vv[e];
            }
        }
        const int npad = N_NODES * (KPAD_DENSE - IN_DIMV);
        for (int p = cb * 256 + tid; p < npad; p += stride) {
            int row = p / (KPAD_DENSE - IN_DIMV);
            int col = IN_DIMV + (p - row * (KPAD_DENSE - IN_DIMV));
            xh[row * KPAD_DENSE + col] = (_Float16)0.f;
        }
    }
}

// ---- CSR build ----
__global__ void hist_gstart_kernel(const int* __restrict__ ei, const int* __restrict__ batch,
                                   int* __restrict__ deg, int* __restrict__ gstart) {
    int e = blockIdx.x * 256 + threadIdx.x;
    if (e < N_EDGES) atomicAdd(&deg[ei[N_EDGES + e]], 1);
    if (e < N_NODES) {
        int b = batch[e];
        int bprev = (e == 0) ? -1 : batch[e - 1];
        for (int g = bprev + 1; g <= b; g++) gstart[g] = e;
        if (e == N_NODES - 1)
            for (int g = b + 1; g <= N_GRAPHS; g++) gstart[g] = N_NODES;
    }
}

__global__ __launch_bounds__(256)
void scan1_kernel(const int* __restrict__ deg, int* __restrict__ bsum) {
    __shared__ int red[256];
    int t = threadIdx.x;
    int i = blockIdx.x * 256 + t;
    red[t] = (i < N_NODES) ? deg[i] : 0;
    __syncthreads();
    for (int s = 128; s > 0; s >>= 1) {
        if (t < s) red[t] += red[t + s];
        __syncthreads();
    }
    if (t == 0) bsum[blockIdx.x] = red[0];
}

__global__ __launch_bounds__(128)
void scan2_kernel(const int* __restrict__ bsum, int* __restrict__ boff) {
    __shared__ int s[128];
    int t = threadIdx.x;
    int v = (t < SCAN_BLOCKS) ? bsum[t] : 0;
    s[t] = v;
    __syncthreads();
    for (int off = 1; off < 128; off <<= 1) {
        int o = (t >= off) ? s[t - off] : 0;
        __syncthreads();
        s[t] += o;
        __syncthreads();
    }
    if (t < SCAN_BLOCKS) boff[t] = s[t] - v;  // exclusive
}

__global__ __launch_bounds__(256)
void scan3_kernel(const int* __restrict__ deg, const int* __restrict__ boff,
                  int* __restrict__ row_start, int* __restrict__ cursor) {
    __shared__ int s[256];
    int t = threadIdx.x;
    int i = blockIdx.x * 256 + t;
    int v = (i < N_NODES) ? deg[i] : 0;
    s[t] = v;
    __syncthreads();
    for (int off = 1; off < 256; off <<= 1) {
        int o = (t >= off) ? s[t - off] : 0;
        __syncthreads();
        s[t] += o;
        __syncthreads();
    }
    int base = boff[blockIdx.x];
    int excl = base + s[t] - v;
    if (i < N_NODES) {
        row_start[i] = excl;
        cursor[i] = excl;
    }
    if (i == N_NODES - 1) row_start[N_NODES] = base + s[t];
}

__global__ void scatter_kernel(const int* __restrict__ ei, int* __restrict__ cursor,
                               int* __restrict__ csr_src) {
    int e = blockIdx.x * 256 + threadIdx.x;
    if (e < N_EDGES) {
        int d = ei[N_EDGES + e];
        int pos = atomicAdd(&cursor[d], 1);
        csr_src[pos] = ei[e];
    }
}

// ============================================================================
// GEMM v8 (pure fp16 operands): C[M,256] = act(A[M,K] @ Bt^T + bias)
//   tile BM=64, BN=128, BK=64; 4 waves, per-wave 32x64 (2x4 frag tiles)
//   Staging: global_load_lds(16B), XOR swizzle.
//   NBUF=2: 48KB LDS, per-step __syncthreads (vmcnt0 drain each step).
//   NBUF=3: 72KB LDS, counted vmcnt(6) pipeline (dense, KSTEPS=12).
//   NBUF=4 (KSTEPS==4): FULL STAGE — 96KB LDS (gfx950 has 160KB/CU),
//     all 24 gll16/thread issued up front, ONE barrier, then 64 MFMAs with
//     zero further syncs. Trades occupancy (1 block/CU) for eliminating the
//     4x per-step vmcnt(0) latency exposure that dominates short-K GEMMs.
//   SUMPART: fused node_summary partials, atomic-free (quadrant-owned nsp).
//   [R8/R9 A/B: SUMPART fusion worth ~25us total; keeper.]
// ============================================================================
template <int KSTEPS, int NBUF, bool GELU_ACT, bool DOT, bool SUMPART>
__global__ __launch_bounds__(256)
void gemm_v8(const _Float16* __restrict__ A, const _Float16* __restrict__ Bt,
             const float* __restrict__ bias, _Float16* __restrict__ C,
             const float* __restrict__ head_w, float* __restrict__ sdot,
             const float* __restrict__ cw, float* __restrict__ nsp) {
    constexpr int KDIM = KSTEPS * 64;  // row stride of A and Bt (elems)
    __shared__ __align__(16) _Float16 Bs[NBUF * 128 * 64];
    __shared__ __align__(16) _Float16 As[NBUF * 64 * 64];

    const int tid = threadIdx.x;
    const int row0 = blockIdx.x * 64;
    const int col0 = blockIdx.y * 128;
    const int wave = tid >> 6, lane = tid & 63;
    const int quad = lane >> 4, lrow = lane & 15;
    const int wrow = wave >> 1, wcol = wave & 1;

    const int sr = tid >> 3;                  // row within 32-row group
    const int scb = (tid & 7) << 4;           // linear byte col (16B aligned)
    const int srcCb = scb ^ ((sr & 7) << 4);  // inverse-swizzled source byte col

    const char* bsrc[4];
#pragma unroll
    for (int i = 0; i < 4; ++i)
        bsrc[i] = (const char*)Bt + (size_t)(col0 + i * 32 + sr) * (KDIM * 2) + srcCb;
    char* const bdst = (char*)&Bs[0] + tid * 16;

    const char* asrc[2];
    char* const adst = (char*)&As[0] + tid * 16;
#pragma unroll
    for (int i = 0; i < 2; ++i) {
        int ar = row0 + i * 32 + sr;
        ar = (ar < N_NODES) ? ar : (N_NODES - 1);
        asrc[i] = (const char*)A + (size_t)ar * (KDIM * 2) + srcCb;
    }

    const int swz = ((lrow & 7) << 4) ^ (quad << 4);
    const int aro0 = (wrow * 32 + lrow) * 128;
    const int aro1 = aro0 + 2048;  // +16 rows
    int bro[4];
#pragma unroll
    for (int t = 0; t < 4; ++t) bro[t] = (wcol * 64 + t * 16 + lrow) * 128;

    f32x4 acc[2][4];
#pragma unroll
    for (int i = 0; i < 2; ++i)
#pragma unroll
        for (int t = 0; t < 4; ++t) acc[i][t] = (f32x4){0.f, 0.f, 0.f, 0.f};

    auto stage = [&](int j) {  // j compile-time under unroll -> all folds
        const int kb = j * 128;
        const int b3 = (j % NBUF) * 16384;
        const int a3 = (j % NBUF) * 8192;
#pragma unroll
        for (int i = 0; i < 4; ++i) gll16(bsrc[i] + kb, bdst + b3 + i * 4096);
#pragma unroll
        for (int i = 0; i < 2; ++i) gll16(asrc[i] + kb, adst + a3 + i * 4096);
    };

    auto compute = [&](int k) {
        const char* pa = (const char*)&As[0] + (k % NBUF) * 8192;
        const char* pb = (const char*)&Bs[0] + (k % NBUF) * 16384;
        if constexpr (NBUF == 3) __builtin_amdgcn_s_setprio(1);
#pragma unroll
        for (int h = 0; h < 2; ++h) {
            const int cbs = (h << 6) ^ swz;
            f16x8 af0 = *(const f16x8*)(pa + aro0 + cbs);
            f16x8 af1 = *(const f16x8*)(pa + aro1 + cbs);
#pragma unroll
            for (int t = 0; t < 4; ++t) {
                f16x8 bf = *(const f16x8*)(pb + bro[t] + cbs);
                acc[0][t] = __builtin_amdgcn_mfma_f32_16x16x32_f16(af0, bf, acc[0][t], 0, 0, 0);
                acc[1][t] = __builtin_amdgcn_mfma_f32_16x16x32_f16(af1, bf, acc[1][t], 0, 0, 0);
            }
        }
        if constexpr (NBUF == 3) __builtin_amdgcn_s_setprio(0);
    };

    if constexpr (NBUF == 4) {
        // ---- full stage: all K-tiles up front, one barrier, pure compute ----
        static_assert(KSTEPS == 4, "NBUF=4 full-stage requires KSTEPS==4");
#pragma unroll
        for (int j = 0; j < KSTEPS; ++j) stage(j);
        __syncthreads();
#pragma unroll
        for (int k = 0; k < KSTEPS; ++k) compute(k);
    } else {
        // ---- prologue ----
        stage(0);
        if constexpr (NBUF == 3) {
            if (KSTEPS > 1) stage(1);
            asm volatile("s_waitcnt vmcnt(6)" ::: "memory");
            __builtin_amdgcn_sched_barrier(0);
            __builtin_amdgcn_s_barrier();
            __builtin_amdgcn_sched_barrier(0);
        } else {
            __syncthreads();
        }

        // ---- main loop ----
#pragma unroll
        for (int k = 0; k < KSTEPS; ++k) {
            const int nxt = k + NBUF - 1;
            if (nxt < KSTEPS) stage(nxt);
            compute(k);
            if (k + 1 < KSTEPS) {
                if constexpr (NBUF == 3) {
                    if (k + 2 < KSTEPS)
                        asm volatile("s_waitcnt vmcnt(6) lgkmcnt(0)" ::: "memory");
                    else
                        asm volatile("s_waitcnt vmcnt(0) lgkmcnt(0)" ::: "memory");
                    __builtin_amdgcn_sched_barrier(0);
                    __builtin_amdgcn_s_barrier();
                    __builtin_amdgcn_sched_barrier(0);
                } else {
                    __syncthreads();
                }
            }
        }
    }

    // ---- epilogue ----
    const int orow = row0 + wrow * 32 + quad * 4;
    const int ocolb = col0 + wcol * 64 + lrow;
    if constexpr (DOT) {
        float dp0[4] = {0.f, 0.f, 0.f, 0.f}, dp1[4] = {0.f, 0.f, 0.f, 0.f};
#pragma unroll
        for (int t = 0; t < 4; ++t) {
            const int col = ocolb + t * 16;
            const float hw = head_w[col];
            const float bv = bias[col];
#pragma unroll
            for (int r = 0; r < 4; ++r) {
                dp0[r] += gelu_exact(acc[0][t][r] + bv) * hw;
                dp1[r] += gelu_exact(acc[1][t][r] + bv) * hw;
            }
        }
#pragma unroll
        for (int r = 0; r < 4; ++r) {
#pragma unroll
            for (int off = 1; off < 16; off <<= 1) {
                dp0[r] += __shfl_xor(dp0[r], off, 64);
                dp1[r] += __shfl_xor(dp1[r], off, 64);
            }
        }
        if (lrow == 0) {
#pragma unroll
            for (int r = 0; r < 4; ++r) {
                if (orow + r < N_NODES) atomicAdd(&sdot[orow + r], dp0[r]);
                if (orow + 16 + r < N_NODES) atomicAdd(&sdot[orow + 16 + r], dp1[r]);
            }
        }
    } else if constexpr (SUMPART) {
        float4 c0v[4], c1v[4];
        float bv[4];
#pragma unroll
        for (int t = 0; t < 4; ++t) {
            const int col = ocolb + t * 16;
            c0v[t] = *(const float4*)&cw[(size_t)col * 4];
            c1v[t] = *(const float4*)&cw[(size_t)(256 + col) * 4];
            bv[t] = bias[col];
        }
        const int part = blockIdx.y * 2 + wcol;
        float* const npbase = nsp + (size_t)part * N_NODES * 12;
#pragma unroll
        for (int h = 0; h < 2; ++h) {
#pragma unroll
            for (int r = 0; r < 4; ++r) {
                const int row = orow + h * 16 + r;
                float p1x = 0.f, p1y = 0.f, p1z = 0.f, p1w = 0.f;
                float p2x = 0.f, p2y = 0.f, p2z = 0.f, p2w = 0.f;
                float q1 = 0.f, q2 = 0.f;
#pragma unroll
                for (int t = 0; t < 4; ++t) {
                    float v = gelu_exact(acc[h][t][r] + bv[t]);
                    _Float16 hv = (_Float16)v;
                    if (row < N_NODES) C[(size_t)row * 256 + (ocolb + t * 16)] = hv;
                    float av = (float)hv;  // match standalone numerics (post-round)
                    p1x += av * c0v[t].x; p1y += av * c0v[t].y;
                    p1z += av * c0v[t].z; p1w += av * c0v[t].w;
                    p2x += av * c1v[t].x; p2y += av * c1v[t].y;
                    p2z += av * c1v[t].z; p2w += av * c1v[t].w;
                    q1 += av; q2 += av * av;
                }
#pragma unroll
                for (int off = 1; off < 16; off <<= 1) {
                    p1x += __shfl_xor(p1x, off, 64); p1y += __shfl_xor(p1y, off, 64);
                    p1z += __shfl_xor(p1z, off, 64); p1w += __shfl_xor(p1w, off, 64);
                    p2x += __shfl_xor(p2x, off, 64); p2y += __shfl_xor(p2y, off, 64);
                    p2z += __shfl_xor(p2z, off, 64); p2w += __shfl_xor(p2w, off, 64);
                    q1 += __shfl_xor(q1, off, 64); q2 += __shfl_xor(q2, off, 64);
                }
                if (lrow == 0 && row < N_NODES) {
                    float* p = npbase + (size_t)row * 12;
                    *(float4*)p = make_float4(p1x, p1y, p1z, p1w);
                    *(float4*)(p + 4) = make_float4(p2x, p2y, p2z, p2w);
                    p[8] = q1;
                    p[9] = q2;
                }
            }
        }
    } else {
#pragma unroll
        for (int t = 0; t < 4; ++t) {
            const int col = ocolb + t * 16;
            const float bv = bias[col];
#pragma unroll
            for (int r = 0; r < 4; ++r) {
                float v0 = acc[0][t][r] + bv;
                float v1 = acc[1][t][r] + bv;
                if constexpr (GELU_ACT) { v0 = gelu_exact(v0); v1 = gelu_exact(v1); }
                if (orow + r < N_NODES)
                    C[(size_t)(orow + r) * 256 + col] = (_Float16)v0;
                if (orow + 16 + r < N_NODES)
                    C[(size_t)(orow + 16 + r) * 256 + col] = (_Float16)v1;
            }
        }
    }
}

// ns = sum of 4 partial quadrants (vectorized float4; 60000 float4s)
__global__ __launch_bounds__(256)
void combine_ns_kernel(const float* __restrict__ nsp, float* __restrict__ ns) {
    int i = blockIdx.x * 256 + threadIdx.x;
    const int n4 = N_NODES * 3;  // 12 floats = 3 float4 per node
    if (i >= n4) return;
    float4 a = ((const float4*)nsp)[i];
    float4 b = ((const float4*)nsp)[i + n4];
    float4 c = ((const float4*)nsp)[i + 2 * n4];
    float4 d = ((const float4*)nsp)[i + 3 * n4];
    ((float4*)ns)[i] = make_float4(a.x + b.x + c.x + d.x, a.y + b.y + c.y + d.y,
                                   a.z + b.z + c.z + d.z, a.w + b.w + c.w + d.w);
}

// ============================================================================
// Fused edge-MLP + CSR SpMM. One wave per node. Per 64-edge chunk:
//   phase 1: lane l computes sigmoid edge weight for chunk edge l (parallel).
//   phase 2: 8-unrolled gather-accumulate; si/wi via __shfl from phase-1 lanes.
// ============================================================================
__global__ __launch_bounds__(256)
void edge_agg_kernel(const _Float16* __restrict__ m, const int* __restrict__ csr_src,
                     const int* __restrict__ row_start, const float* __restrict__ ns,
                     const float* __restrict__ x_pos, const float* __restrict__ cw,
                     const float* __restrict__ SgSb, const float* __restrict__ w1_b,
                     const float* __restrict__ ln2_g, const float* __restrict__ ln2_b,
                     const float* __restrict__ w2_w, const float* __restrict__ w2_b,
                     _Float16* __restrict__ agg) {
    int n = blockIdx.x * 4 + (threadIdx.x >> 6);
    if (n >= N_NODES) return;
    int lane = threadIdx.x & 63;

    // wave-uniform per-node values
    const float* nsd = &ns[(size_t)n * 12];
    float4 p2d = *(const float4*)(nsd + 4);
    float nsd8 = nsd[8], nsd9 = nsd[9];
    float pxn[3] = {x_pos[(size_t)n * 3 + 0], x_pos[(size_t)n * 3 + 1],
                    x_pos[(size_t)n * 3 + 2]};
    // uniform constants
    float4 cwp[6];
#pragma unroll
    for (int k = 0; k < 6; ++k) cwp[k] = *(const float4*)&cw[(size_t)(512 + k) * 4];
    float sgv[8];
#pragma unroll
    for (int k = 0; k < 8; ++k) sgv[k] = SgSb[k];
    float w1bv[4], l2g[4], l2b[4], w2wv[4];
#pragma unroll
    for (int k = 0; k < 4; ++k) {
        w1bv[k] = w1_b[k]; l2g[k] = ln2_g[k]; l2b[k] = ln2_b[k]; w2wv[k] = w2_w[k];
    }
    const float w2bv = w2_b[0];

    int beg = row_start[n], end = row_start[n + 1];
    float a0 = 0.f, a1 = 0.f, a2 = 0.f, a3 = 0.f;

    for (int cb = beg; cb < end; cb += 64) {
        int cnt = min(64, end - cb);
        // ---- phase 1: parallel edge weights ----
        float w = 0.f;
        int s = 0;
        if (lane < cnt) {
            s = csr_src[cb + lane];
            const float* nss = &ns[(size_t)s * 12];
            float4 p1 = *(const float4*)nss;
            float S1 = nss[8] + nsd8;
            float S2 = nss[9] + nsd9;
            float D[4] = {p1.x + p2d.x, p1.y + p2d.y, p1.z + p2d.z, p1.w + p2d.w};
            float ps[6];
            ps[0] = x_pos[(size_t)s * 3 + 0];
            ps[1] = x_pos[(size_t)s * 3 + 1];
            ps[2] = x_pos[(size_t)s * 3 + 2];
            ps[3] = pxn[0]; ps[4] = pxn[1]; ps[5] = pxn[2];
#pragma unroll
            for (int k = 0; k < 6; ++k) {
                S1 += ps[k];
                S2 += ps[k] * ps[k];
                D[0] += ps[k] * cwp[k].x; D[1] += ps[k] * cwp[k].y;
                D[2] += ps[k] * cwp[k].z; D[3] += ps[k] * cwp[k].w;
            }
            const float inv = 1.f / 518.f;
            float mu = S1 * inv;
            float var = fmaf(-mu, mu, S2 * inv);
            float rstd = rsqrtf(var + LN_EPS);
            float t[4];
#pragma unroll
            for (int c = 0; c < 4; ++c)
                t[c] = gelu_exact(rstd * (D[c] - mu * sgv[c]) + sgv[4 + c] + w1bv[c]);
            float mu2 = 0.25f * (t[0] + t[1] + t[2] + t[3]);
            float var2 = 0.25f * ((t[0] - mu2) * (t[0] - mu2) + (t[1] - mu2) * (t[1] - mu2) +
                                  (t[2] - mu2) * (t[2] - mu2) + (t[3] - mu2) * (t[3] - mu2));
            float r2 = rsqrtf(var2 + LN_EPS);
            float z = w2bv;
#pragma unroll
            for (int c = 0; c < 4; ++c)
                z += ((t[c] - mu2) * r2 * l2g[c] + l2b[c]) * w2wv[c];
            w = 1.f / (1.f + expf(-z));
        }
        // ---- phase 2: gather-accumulate (CSR order preserved) ----
        int u = 0;
        for (; u + 8 <= cnt; u += 8) {
            int si[8];
            float wi[8];
#pragma unroll
            for (int uu = 0; uu < 8; ++uu) {
                si[uu] = __shfl(s, u + uu, 64);
                wi[uu] = __shfl(w, u + uu, 64);
            }
            f16x4 v[8];
#pragma unroll
            for (int uu = 0; uu < 8; ++uu)
                v[uu] = *(const f16x4*)&m[(size_t)si[uu] * CDIM + lane * 4];
#pragma unroll
            for (int uu = 0; uu < 8; ++uu) {
                a0 = fmaf(wi[uu], (float)v[uu][0], a0);
                a1 = fmaf(wi[uu], (float)v[uu][1], a1);
                a2 = fmaf(wi[uu], (float)v[uu][2], a2);
                a3 = fmaf(wi[uu], (float)v[uu][3], a3);
            }
        }
        for (; u < cnt; ++u) {
            int si = __shfl(s, u, 64);
            float wi = __shfl(w, u, 64);
            f16x4 v = *(const f16x4*)&m[(size_t)si * CDIM + lane * 4];
            a0 = fmaf(wi, (float)v[0], a0);
            a1 = fmaf(wi, (float)v[1], a1);
            a2 = fmaf(wi, (float)v[2], a2);
            a3 = fmaf(wi, (float)v[3], a3);
        }
    }
    f16x4 o;
    o[0] = (_Float16)a0; o[1] = (_Float16)a1; o[2] = (_Float16)a2; o[3] = (_Float16)a3;
    *(f16x4*)&agg[(size_t)n * CDIM + lane * 4] = o;
}

__global__ __launch_bounds__(256)
void final_head_kernel(const float* __restrict__ sdot, const int* __restrict__ gstart,
                       const float* __restrict__ head_b, float* __restrict__ out) {
    int g = blockIdx.x;
    int t = threadIdx.x;
    int beg = gstart[g], end = gstart[g + 1];
    float s = 0.f;
    for (int i = beg + t; i < end; i += 256) s += sdot[i];
    __shared__ float red[256];
    red[t] = s;
    __syncthreads();
    for (int k = 128; k > 0; k >>= 1) {
        if (t < k) red[t] += red[t + k];
        __syncthreads();
    }
    if (t == 0) out[g] = red[0] / fmaxf((float)(end - beg), 1.f) + head_b[0];
}

extern "C" void kernel_launch(void* const* d_in, const int* in_sizes, int n_in,
                              void* d_out, int out_size, void* d_ws, size_t ws_size,
                              hipStream_t stream) {
    const float* x       = (const float*)d_in[0];
    const float* x_pos   = (const float*)d_in[1];
    const int*   ei      = (const int*)d_in[2];
    const int*   batch   = (const int*)d_in[3];
    const float* dense_w = (const float*)d_in[4];
    const float* dense_b = (const float*)d_in[5];
    const float* d1_w    = (const float*)d_in[6];
    const float* d1_b    = (const float*)d_in[7];
    const float* ln1_g   = (const float*)d_in[8];
    const float* ln1_b   = (const float*)d_in[9];
    const float* w1_w    = (const float*)d_in[10];
    const float* w1_b    = (const float*)d_in[11];
    const float* ln2_g   = (const float*)d_in[12];
    const float* ln2_b   = (const float*)d_in[13];
    const float* w2_w    = (const float*)d_in[14];
    const float* w2_b    = (const float*)d_in[15];
    const float* d2_w    = (const float*)d_in[16];
    const float* d2_b    = (const float*)d_in[17];
    const float* head_w  = (const float*)d_in[18];
    const float* head_b  = (const float*)d_in[19];
    float* out = (float*)d_out;

    _Float16* hbuf0 = (_Float16*)d_ws;                          // [N][256] fp16
    _Float16* hbuf1 = hbuf0 + (size_t)N_NODES * CDIM;           // [N][256] fp16
    _Float16* wt_dense = hbuf1 + (size_t)N_NODES * CDIM;        // [256][768] fp16
    _Float16* wt_sq    = wt_dense + (size_t)256 * KPAD_DENSE;   // [8][256][256] fp16
    _Float16* x_h      = wt_sq + (size_t)8 * 256 * 256;         // [N][768] fp16
    float* cw    = (float*)(x_h + (size_t)N_NODES * KPAD_DENSE);// [L][518][4]
    float* SgSb  = cw + (size_t)NLAYERS * ED_DIM * 4;           // [L][8]
    float* ns    = SgSb + NLAYERS * 8;                          // [N][12]
    float* nsp   = ns + (size_t)N_NODES * 12;                   // [4][N][12]
    float* sdot  = nsp + (size_t)4 * N_NODES * 12;              // [N]
    int* gstart    = (int*)(sdot + N_NODES);                    // [33]
    int* deg       = gstart + N_GRAPHS + 1;                     // [N]
    int* row_start = deg + N_NODES;                             // [N+1]
    int* cursor    = row_start + N_NODES + 1;                   // [N]
    int* csr_src   = cursor + N_NODES;                          // [E]
    int* bsum      = csr_src + N_EDGES;                         // [SCAN_BLOCKS]
    int* boff      = bsum + SCAN_BLOCKS;                        // [SCAN_BLOCKS]

    prep_all<<<2914, 256, 0, stream>>>(ln1_g, ln1_b, w1_w, cw, SgSb,
                                       dense_w, wt_dense, d1_w, d2_w, wt_sq, deg,
                                       sdot, x, x_h);

    hist_gstart_kernel<<<(N_EDGES + 255) / 256, 256, 0, stream>>>(ei, batch, deg, gstart);
    scan1_kernel<<<SCAN_BLOCKS, 256, 0, stream>>>(deg, bsum);
    scan2_kernel<<<1, 128, 0, stream>>>(bsum, boff);
    scan3_kernel<<<SCAN_BLOCKS, 256, 0, stream>>>(deg, boff, row_start, cursor);
    scatter_kernel<<<(N_EDGES + 255) / 256, 256, 0, stream>>>(ei, cursor, csr_src);

    const dim3 G2((N_NODES + 63) / 64, 2);  // (313, 2) = 626 blocks
    gemm_v8<12, 3, false, false, false><<<G2, 256, 0, stream>>>(
        x_h, wt_dense, dense_b, hbuf0, nullptr, nullptr, nullptr, nullptr);

    _Float16* h = hbuf0;
    _Float16* other = hbuf1;
    for (int l = 0; l < NLAYERS; l++) {
        // d1 GEMM with fused summary partials (atomic-free), full-stage NBUF=4
        gemm_v8<4, 4, true, false, true><<<G2, 256, 0, stream>>>(
            h, wt_sq + (size_t)l * 65536, d1_b + l * CDIM, other, nullptr, nullptr,
            cw + (size_t)l * ED_DIM * 4, nsp);
        combine_ns_kernel<<<(N_NODES * 3 + 255) / 256, 256, 0, stream>>>(nsp, ns);
        edge_agg_kernel<<<(N_NODES + 3) / 4, 256, 0, stream>>>(
            other, csr_src, row_start, ns, x_pos, cw + (size_t)l * ED_DIM * 4,
            SgSb + l * 8, w1_b + l * 4, ln2_g + l * 4, ln2_b + l * 4,
            w2_w + l * 4, w2_b + l, h);
        if (l < NLAYERS - 1) {
            gemm_v8<4, 4, true, false, false><<<G2, 256, 0, stream>>>(
                h, wt_sq + (size_t)(4 + l) * 65536, d2_b + l * CDIM, other, nullptr, nullptr,
                nullptr, nullptr);
        } else {
            // final layer: fuse node_dot into the epilogue, skip C-write
            gemm_v8<4, 4, true, true, false><<<G2, 256, 0, stream>>>(
                h, wt_sq + (size_t)(4 + l) * 65536, d2_b + l * CDIM, other, head_w, sdot,
                nullptr, nullptr);
        }
        _Float16* tmp = h; h = other; other = tmp;
    }

    final_head_kernel<<<N_GRAPHS, 256, 0, stream>>>(sdot, gstart, head_b, out);
}

// Round 11
// 467.548 us; speedup vs baseline: 1.1520x; 1.1520x over previous
//
#include <hip/hip_runtime.h>
#include <math.h>

#define N_NODES 20000
#define N_EDGES 320000
#define N_GRAPHS 32
#define CDIM 256
#define IN_DIMV 739
#define KPAD_DENSE 768
#define ED_DIM 518
#define NLAYERS 4
#define LN_EPS 1e-5f
#define SCAN_BLOCKS ((N_NODES + 255) / 256)  // 79

typedef _Float16 f16x8 __attribute__((ext_vector_type(8)));
typedef _Float16 f16x4 __attribute__((ext_vector_type(4)));
typedef float f32x4 __attribute__((ext_vector_type(4)));

__device__ __forceinline__ float gelu_exact(float x) {
    return 0.5f * x * (1.f + erff(x * 0.7071067811865475f));
}

__device__ __forceinline__ void gll16(const void* g, void* l) {
    __builtin_amdgcn_global_load_lds((const __attribute__((address_space(1))) void*)g,
                                     (__attribute__((address_space(3))) void*)l, 16, 0, 0);
}

// ---- merged setup: zero deg | cw/SgSb | dense W | sq W | zero sdot |
//      convert x fp32->fp16 padded ----
__global__ __launch_bounds__(256)
void prep_all(const float* __restrict__ ln1_g, const float* __restrict__ ln1_b,
              const float* __restrict__ w1_w, float* __restrict__ cw,
              float* __restrict__ SgSb,
              const float* __restrict__ dense_w, _Float16* __restrict__ wt_dense,
              const float* __restrict__ d1_w, const float* __restrict__ d2_w,
              _Float16* __restrict__ wt_sq, int* __restrict__ deg,
              float* __restrict__ sdot,
              const float* __restrict__ x, _Float16* __restrict__ xh) {
    __shared__ float smem[2048 + 64];
    int b = blockIdx.x, tid = threadIdx.x;
    if (b < 79) {
        int i = b * 256 + tid;
        if (i < N_NODES) deg[i] = 0;
    } else if (b < 83) {
        int l = b - 79;
        float sg[4] = {0, 0, 0, 0}, sb[4] = {0, 0, 0, 0};
        for (int i = tid; i < ED_DIM; i += 256) {
            float g = ln1_g[l * ED_DIM + i];
            float bb = ln1_b[l * ED_DIM + i];
            float4 w = *(const float4*)&w1_w[(size_t)(l * ED_DIM + i) * 4];
            float4 c = make_float4(g * w.x, g * w.y, g * w.z, g * w.w);
            *(float4*)&cw[(size_t)(l * ED_DIM + i) * 4] = c;
            sg[0] += c.x; sg[1] += c.y; sg[2] += c.z; sg[3] += c.w;
            sb[0] += bb * w.x; sb[1] += bb * w.y; sb[2] += bb * w.z; sb[3] += bb * w.w;
        }
        for (int c = 0; c < 4; c++) { smem[tid * 8 + c] = sg[c]; smem[tid * 8 + 4 + c] = sb[c]; }
        __syncthreads();
        for (int s = 128; s > 0; s >>= 1) {
            if (tid < s)
                for (int c = 0; c < 8; c++) smem[tid * 8 + c] += smem[(tid + s) * 8 + c];
            __syncthreads();
        }
        if (tid < 8) SgSb[l * 8 + tid] = smem[tid];
    } else if (b < 275) {
        int q = b - 83;
        int kt = q >> 3, nt = q & 7;
        int i = tid >> 5, j = tid & 31;
        float* T = smem;  // [32][33]
#pragma unroll
        for (int ii = 0; ii < 4; ii++) {
            int k = kt * 32 + i + ii * 8;
            T[(i + ii * 8) * 33 + j] = (k < IN_DIMV) ? dense_w[(size_t)k * 256 + nt * 32 + j] : 0.f;
        }
        __syncthreads();
#pragma unroll
        for (int ii = 0; ii < 4; ii++) {
            int n = nt * 32 + i + ii * 8;
            wt_dense[(size_t)n * KPAD_DENSE + kt * 32 + j] = (_Float16)T[j * 33 + i + ii * 8];
        }
    } else if (b < 787) {
        int q = b - 275;
        int z = q >> 6, kt = (q >> 3) & 7, nt = q & 7;
        const float* W = (z < 4) ? d1_w + (size_t)z * 65536 : d2_w + (size_t)(z - 4) * 65536;
        _Float16* O = wt_sq + (size_t)z * 65536;
        int i = tid >> 5, j = tid & 31;
        float* T = smem;
#pragma unroll
        for (int ii = 0; ii < 4; ii++)
            T[(i + ii * 8) * 33 + j] = W[(size_t)(kt * 32 + i + ii * 8) * 256 + nt * 32 + j];
        __syncthreads();
#pragma unroll
        for (int ii = 0; ii < 4; ii++)
            O[(size_t)(nt * 32 + i + ii * 8) * 256 + kt * 32 + j] = (_Float16)T[j * 33 + i + ii * 8];
    } else if (b < 866) {
        int i = (b - 787) * 256 + tid;
        if (i < N_NODES) sdot[i] = 0.f;
    } else {
        // convert x [N][739] fp32 -> xh [N][768] fp16, zero-padded
        const int cb = b - 866;                 // 2048 blocks
        const int stride = 2048 * 256;
        const int nquads = (N_NODES * IN_DIMV) / 4;
        for (int q = cb * 256 + tid; q < nquads; q += stride) {
            float4 v = ((const float4*)x)[q];
            int base = q * 4;
            float vv[4] = {v.x, v.y, v.z, v.w};
#pragma unroll
            for (int e = 0; e < 4; ++e) {
                int idx = base + e;
                int row = idx / IN_DIMV;
                int col = idx - row * IN_DIMV;
                xh[row * KPAD_DENSE + col] = (_Float16)vv[e];
            }
        }
        const int npad = N_NODES * (KPAD_DENSE - IN_DIMV);
        for (int p = cb * 256 + tid; p < npad; p += stride) {
            int row = p / (KPAD_DENSE - IN_DIMV);
            int col = IN_DIMV + (p - row * (KPAD_DENSE - IN_DIMV));
            xh[row * KPAD_DENSE + col] = (_Float16)0.f;
        }
    }
}

// ---- CSR build ----
__global__ void hist_gstart_kernel(const int* __restrict__ ei, const int* __restrict__ batch,
                                   int* __restrict__ deg, int* __restrict__ gstart) {
    int e = blockIdx.x * 256 + threadIdx.x;
    if (e < N_EDGES) atomicAdd(&deg[ei[N_EDGES + e]], 1);
    if (e < N_NODES) {
        int b = batch[e];
        int bprev = (e == 0) ? -1 : batch[e - 1];
        for (int g = bprev + 1; g <= b; g++) gstart[g] = e;
        if (e == N_NODES - 1)
            for (int g = b + 1; g <= N_GRAPHS; g++) gstart[g] = N_NODES;
    }
}

__global__ __launch_bounds__(256)
void scan1_kernel(const int* __restrict__ deg, int* __restrict__ bsum) {
    __shared__ int red[256];
    int t = threadIdx.x;
    int i = blockIdx.x * 256 + t;
    red[t] = (i < N_NODES) ? deg[i] : 0;
    __syncthreads();
    for (int s = 128; s > 0; s >>= 1) {
        if (t < s) red[t] += red[t + s];
        __syncthreads();
    }
    if (t == 0) bsum[blockIdx.x] = red[0];
}

__global__ __launch_bounds__(128)
void scan2_kernel(const int* __restrict__ bsum, int* __restrict__ boff) {
    __shared__ int s[128];
    int t = threadIdx.x;
    int v = (t < SCAN_BLOCKS) ? bsum[t] : 0;
    s[t] = v;
    __syncthreads();
    for (int off = 1; off < 128; off <<= 1) {
        int o = (t >= off) ? s[t - off] : 0;
        __syncthreads();
        s[t] += o;
        __syncthreads();
    }
    if (t < SCAN_BLOCKS) boff[t] = s[t] - v;  // exclusive
}

__global__ __launch_bounds__(256)
void scan3_kernel(const int* __restrict__ deg, const int* __restrict__ boff,
                  int* __restrict__ row_start, int* __restrict__ cursor) {
    __shared__ int s[256];
    int t = threadIdx.x;
    int i = blockIdx.x * 256 + t;
    int v = (i < N_NODES) ? deg[i] : 0;
    s[t] = v;
    __syncthreads();
    for (int off = 1; off < 256; off <<= 1) {
        int o = (t >= off) ? s[t - off] : 0;
        __syncthreads();
        s[t] += o;
        __syncthreads();
    }
    int base = boff[blockIdx.x];
    int excl = base + s[t] - v;
    if (i < N_NODES) {
        row_start[i] = excl;
        cursor[i] = excl;
    }
    if (i == N_NODES - 1) row_start[N_NODES] = base + s[t];
}

__global__ void scatter_kernel(const int* __restrict__ ei, int* __restrict__ cursor,
                               int* __restrict__ csr_src) {
    int e = blockIdx.x * 256 + threadIdx.x;
    if (e < N_EDGES) {
        int d = ei[N_EDGES + e];
        int pos = atomicAdd(&cursor[d], 1);
        csr_src[pos] = ei[e];
    }
}

// ============================================================================
// GEMM v6 (pure fp16 operands): C[M,256] = act(A[M,K] @ Bt^T + bias)
//   tile BM=64, BN=128, BK=64; 4 waves, per-wave 32x64 (2x4 frag tiles)
//   Staging: global_load_lds(16B), XOR swizzle. NBUF=2: __syncthreads
//   schedule (48KB LDS, 3 blocks/CU — R10 A/B: full-stage NBUF=4 at 96KB
//   LDS/1 block/CU cost +63us total; occupancy > sync-elimination here).
//   NBUF=3: counted vmcnt(6) pipeline (dense, KSTEPS=12).
//   SUMPART: fused node_summary partials, atomic-free (quadrant-owned nsp).
//   [R8/R9 A/B: SUMPART fusion worth ~25us total; keeper.]
// ============================================================================
template <int KSTEPS, int NBUF, bool GELU_ACT, bool DOT, bool SUMPART>
__global__ __launch_bounds__(256)
void gemm_v6(const _Float16* __restrict__ A, const _Float16* __restrict__ Bt,
             const float* __restrict__ bias, _Float16* __restrict__ C,
             const float* __restrict__ head_w, float* __restrict__ sdot,
             const float* __restrict__ cw, float* __restrict__ nsp) {
    constexpr int KDIM = KSTEPS * 64;  // row stride of A and Bt (elems)
    __shared__ __align__(16) _Float16 Bs[NBUF * 128 * 64];
    __shared__ __align__(16) _Float16 As[NBUF * 64 * 64];

    const int tid = threadIdx.x;
    const int row0 = blockIdx.x * 64;
    const int col0 = blockIdx.y * 128;
    const int wave = tid >> 6, lane = tid & 63;
    const int quad = lane >> 4, lrow = lane & 15;
    const int wrow = wave >> 1, wcol = wave & 1;

    const int sr = tid >> 3;                  // row within 32-row group
    const int scb = (tid & 7) << 4;           // linear byte col (16B aligned)
    const int srcCb = scb ^ ((sr & 7) << 4);  // inverse-swizzled source byte col

    const char* bsrc[4];
#pragma unroll
    for (int i = 0; i < 4; ++i)
        bsrc[i] = (const char*)Bt + (size_t)(col0 + i * 32 + sr) * (KDIM * 2) + srcCb;
    char* const bdst = (char*)&Bs[0] + tid * 16;

    const char* asrc[2];
    char* const adst = (char*)&As[0] + tid * 16;
#pragma unroll
    for (int i = 0; i < 2; ++i) {
        int ar = row0 + i * 32 + sr;
        ar = (ar < N_NODES) ? ar : (N_NODES - 1);
        asrc[i] = (const char*)A + (size_t)ar * (KDIM * 2) + srcCb;
    }

    const int swz = ((lrow & 7) << 4) ^ (quad << 4);
    const int aro0 = (wrow * 32 + lrow) * 128;
    const int aro1 = aro0 + 2048;  // +16 rows
    int bro[4];
#pragma unroll
    for (int t = 0; t < 4; ++t) bro[t] = (wcol * 64 + t * 16 + lrow) * 128;

    f32x4 acc[2][4];
#pragma unroll
    for (int i = 0; i < 2; ++i)
#pragma unroll
        for (int t = 0; t < 4; ++t) acc[i][t] = (f32x4){0.f, 0.f, 0.f, 0.f};

    auto stage = [&](int j) {  // j compile-time under unroll -> all folds
        const int kb = j * 128;
        const int b3 = (j % NBUF) * 16384;
        const int a3 = (j % NBUF) * 8192;
#pragma unroll
        for (int i = 0; i < 4; ++i) gll16(bsrc[i] + kb, bdst + b3 + i * 4096);
#pragma unroll
        for (int i = 0; i < 2; ++i) gll16(asrc[i] + kb, adst + a3 + i * 4096);
    };

    auto compute = [&](int k) {
        const char* pa = (const char*)&As[0] + (k % NBUF) * 8192;
        const char* pb = (const char*)&Bs[0] + (k % NBUF) * 16384;
        if constexpr (NBUF == 3) __builtin_amdgcn_s_setprio(1);
#pragma unroll
        for (int h = 0; h < 2; ++h) {
            const int cbs = (h << 6) ^ swz;
            f16x8 af0 = *(const f16x8*)(pa + aro0 + cbs);
            f16x8 af1 = *(const f16x8*)(pa + aro1 + cbs);
#pragma unroll
            for (int t = 0; t < 4; ++t) {
                f16x8 bf = *(const f16x8*)(pb + bro[t] + cbs);
                acc[0][t] = __builtin_amdgcn_mfma_f32_16x16x32_f16(af0, bf, acc[0][t], 0, 0, 0);
                acc[1][t] = __builtin_amdgcn_mfma_f32_16x16x32_f16(af1, bf, acc[1][t], 0, 0, 0);
            }
        }
        if constexpr (NBUF == 3) __builtin_amdgcn_s_setprio(0);
    };

    // ---- prologue ----
    stage(0);
    if constexpr (NBUF == 3) {
        if (KSTEPS > 1) stage(1);
        asm volatile("s_waitcnt vmcnt(6)" ::: "memory");
        __builtin_amdgcn_sched_barrier(0);
        __builtin_amdgcn_s_barrier();
        __builtin_amdgcn_sched_barrier(0);
    } else {
        __syncthreads();
    }

    // ---- main loop ----
#pragma unroll
    for (int k = 0; k < KSTEPS; ++k) {
        const int nxt = k + NBUF - 1;
        if (nxt < KSTEPS) stage(nxt);
        compute(k);
        if (k + 1 < KSTEPS) {
            if constexpr (NBUF == 3) {
                if (k + 2 < KSTEPS)
                    asm volatile("s_waitcnt vmcnt(6) lgkmcnt(0)" ::: "memory");
                else
                    asm volatile("s_waitcnt vmcnt(0) lgkmcnt(0)" ::: "memory");
                __builtin_amdgcn_sched_barrier(0);
                __builtin_amdgcn_s_barrier();
                __builtin_amdgcn_sched_barrier(0);
            } else {
                __syncthreads();
            }
        }
    }

    // ---- epilogue ----
    const int orow = row0 + wrow * 32 + quad * 4;
    const int ocolb = col0 + wcol * 64 + lrow;
    if constexpr (DOT) {
        float dp0[4] = {0.f, 0.f, 0.f, 0.f}, dp1[4] = {0.f, 0.f, 0.f, 0.f};
#pragma unroll
        for (int t = 0; t < 4; ++t) {
            const int col = ocolb + t * 16;
            const float hw = head_w[col];
            const float bv = bias[col];
#pragma unroll
            for (int r = 0; r < 4; ++r) {
                dp0[r] += gelu_exact(acc[0][t][r] + bv) * hw;
                dp1[r] += gelu_exact(acc[1][t][r] + bv) * hw;
            }
        }
#pragma unroll
        for (int r = 0; r < 4; ++r) {
#pragma unroll
            for (int off = 1; off < 16; off <<= 1) {
                dp0[r] += __shfl_xor(dp0[r], off, 64);
                dp1[r] += __shfl_xor(dp1[r], off, 64);
            }
        }
        if (lrow == 0) {
#pragma unroll
            for (int r = 0; r < 4; ++r) {
                if (orow + r < N_NODES) atomicAdd(&sdot[orow + r], dp0[r]);
                if (orow + 16 + r < N_NODES) atomicAdd(&sdot[orow + 16 + r], dp1[r]);
            }
        }
    } else if constexpr (SUMPART) {
        float4 c0v[4], c1v[4];
        float bv[4];
#pragma unroll
        for (int t = 0; t < 4; ++t) {
            const int col = ocolb + t * 16;
            c0v[t] = *(const float4*)&cw[(size_t)col * 4];
            c1v[t] = *(const float4*)&cw[(size_t)(256 + col) * 4];
            bv[t] = bias[col];
        }
        const int part = blockIdx.y * 2 + wcol;
        float* const npbase = nsp + (size_t)part * N_NODES * 12;
#pragma unroll
        for (int h = 0; h < 2; ++h) {
#pragma unroll
            for (int r = 0; r < 4; ++r) {
                const int row = orow + h * 16 + r;
                float p1x = 0.f, p1y = 0.f, p1z = 0.f, p1w = 0.f;
                float p2x = 0.f, p2y = 0.f, p2z = 0.f, p2w = 0.f;
                float q1 = 0.f, q2 = 0.f;
#pragma unroll
                for (int t = 0; t < 4; ++t) {
                    float v = gelu_exact(acc[h][t][r] + bv[t]);
                    _Float16 hv = (_Float16)v;
                    if (row < N_NODES) C[(size_t)row * 256 + (ocolb + t * 16)] = hv;
                    float av = (float)hv;  // match standalone numerics (post-round)
                    p1x += av * c0v[t].x; p1y += av * c0v[t].y;
                    p1z += av * c0v[t].z; p1w += av * c0v[t].w;
                    p2x += av * c1v[t].x; p2y += av * c1v[t].y;
                    p2z += av * c1v[t].z; p2w += av * c1v[t].w;
                    q1 += av; q2 += av * av;
                }
#pragma unroll
                for (int off = 1; off < 16; off <<= 1) {
                    p1x += __shfl_xor(p1x, off, 64); p1y += __shfl_xor(p1y, off, 64);
                    p1z += __shfl_xor(p1z, off, 64); p1w += __shfl_xor(p1w, off, 64);
                    p2x += __shfl_xor(p2x, off, 64); p2y += __shfl_xor(p2y, off, 64);
                    p2z += __shfl_xor(p2z, off, 64); p2w += __shfl_xor(p2w, off, 64);
                    q1 += __shfl_xor(q1, off, 64); q2 += __shfl_xor(q2, off, 64);
                }
                if (lrow == 0 && row < N_NODES) {
                    float* p = npbase + (size_t)row * 12;
                    *(float4*)p = make_float4(p1x, p1y, p1z, p1w);
                    *(float4*)(p + 4) = make_float4(p2x, p2y, p2z, p2w);
                    p[8] = q1;
                    p[9] = q2;
                }
            }
        }
    } else {
#pragma unroll
        for (int t = 0; t < 4; ++t) {
            const int col = ocolb + t * 16;
            const float bv = bias[col];
#pragma unroll
            for (int r = 0; r < 4; ++r) {
                float v0 = acc[0][t][r] + bv;
                float v1 = acc[1][t][r] + bv;
                if constexpr (GELU_ACT) { v0 = gelu_exact(v0); v1 = gelu_exact(v1); }
                if (orow + r < N_NODES)
                    C[(size_t)(orow + r) * 256 + col] = (_Float16)v0;
                if (orow + 16 + r < N_NODES)
                    C[(size_t)(orow + 16 + r) * 256 + col] = (_Float16)v1;
            }
        }
    }
}

// ns = sum of 4 partial quadrants (vectorized float4; 60000 float4s)
__global__ __launch_bounds__(256)
void combine_ns_kernel(const float* __restrict__ nsp, float* __restrict__ ns) {
    int i = blockIdx.x * 256 + threadIdx.x;
    const int n4 = N_NODES * 3;  // 12 floats = 3 float4 per node
    if (i >= n4) return;
    float4 a = ((const float4*)nsp)[i];
    float4 b = ((const float4*)nsp)[i + n4];
    float4 c = ((const float4*)nsp)[i + 2 * n4];
    float4 d = ((const float4*)nsp)[i + 3 * n4];
    ((float4*)ns)[i] = make_float4(a.x + b.x + c.x + d.x, a.y + b.y + c.y + d.y,
                                   a.z + b.z + c.z + d.z, a.w + b.w + c.w + d.w);
}

// ============================================================================
// Fused edge-MLP + CSR SpMM. One wave per node. Per 64-edge chunk:
//   phase 1: lane l computes sigmoid edge weight for chunk edge l (parallel).
//   phase 2: 8-unrolled gather-accumulate; si/wi via __shfl from phase-1 lanes.
// ============================================================================
__global__ __launch_bounds__(256)
void edge_agg_kernel(const _Float16* __restrict__ m, const int* __restrict__ csr_src,
                     const int* __restrict__ row_start, const float* __restrict__ ns,
                     const float* __restrict__ x_pos, const float* __restrict__ cw,
                     const float* __restrict__ SgSb, const float* __restrict__ w1_b,
                     const float* __restrict__ ln2_g, const float* __restrict__ ln2_b,
                     const float* __restrict__ w2_w, const float* __restrict__ w2_b,
                     _Float16* __restrict__ agg) {
    int n = blockIdx.x * 4 + (threadIdx.x >> 6);
    if (n >= N_NODES) return;
    int lane = threadIdx.x & 63;

    // wave-uniform per-node values
    const float* nsd = &ns[(size_t)n * 12];
    float4 p2d = *(const float4*)(nsd + 4);
    float nsd8 = nsd[8], nsd9 = nsd[9];
    float pxn[3] = {x_pos[(size_t)n * 3 + 0], x_pos[(size_t)n * 3 + 1],
                    x_pos[(size_t)n * 3 + 2]};
    // uniform constants
    float4 cwp[6];
#pragma unroll
    for (int k = 0; k < 6; ++k) cwp[k] = *(const float4*)&cw[(size_t)(512 + k) * 4];
    float sgv[8];
#pragma unroll
    for (int k = 0; k < 8; ++k) sgv[k] = SgSb[k];
    float w1bv[4], l2g[4], l2b[4], w2wv[4];
#pragma unroll
    for (int k = 0; k < 4; ++k) {
        w1bv[k] = w1_b[k]; l2g[k] = ln2_g[k]; l2b[k] = ln2_b[k]; w2wv[k] = w2_w[k];
    }
    const float w2bv = w2_b[0];

    int beg = row_start[n], end = row_start[n + 1];
    float a0 = 0.f, a1 = 0.f, a2 = 0.f, a3 = 0.f;

    for (int cb = beg; cb < end; cb += 64) {
        int cnt = min(64, end - cb);
        // ---- phase 1: parallel edge weights ----
        float w = 0.f;
        int s = 0;
        if (lane < cnt) {
            s = csr_src[cb + lane];
            const float* nss = &ns[(size_t)s * 12];
            float4 p1 = *(const float4*)nss;
            float S1 = nss[8] + nsd8;
            float S2 = nss[9] + nsd9;
            float D[4] = {p1.x + p2d.x, p1.y + p2d.y, p1.z + p2d.z, p1.w + p2d.w};
            float ps[6];
            ps[0] = x_pos[(size_t)s * 3 + 0];
            ps[1] = x_pos[(size_t)s * 3 + 1];
            ps[2] = x_pos[(size_t)s * 3 + 2];
            ps[3] = pxn[0]; ps[4] = pxn[1]; ps[5] = pxn[2];
#pragma unroll
            for (int k = 0; k < 6; ++k) {
                S1 += ps[k];
                S2 += ps[k] * ps[k];
                D[0] += ps[k] * cwp[k].x; D[1] += ps[k] * cwp[k].y;
                D[2] += ps[k] * cwp[k].z; D[3] += ps[k] * cwp[k].w;
            }
            const float inv = 1.f / 518.f;
            float mu = S1 * inv;
            float var = fmaf(-mu, mu, S2 * inv);
            float rstd = rsqrtf(var + LN_EPS);
            float t[4];
#pragma unroll
            for (int c = 0; c < 4; ++c)
                t[c] = gelu_exact(rstd * (D[c] - mu * sgv[c]) + sgv[4 + c] + w1bv[c]);
            float mu2 = 0.25f * (t[0] + t[1] + t[2] + t[3]);
            float var2 = 0.25f * ((t[0] - mu2) * (t[0] - mu2) + (t[1] - mu2) * (t[1] - mu2) +
                                  (t[2] - mu2) * (t[2] - mu2) + (t[3] - mu2) * (t[3] - mu2));
            float r2 = rsqrtf(var2 + LN_EPS);
            float z = w2bv;
#pragma unroll
            for (int c = 0; c < 4; ++c)
                z += ((t[c] - mu2) * r2 * l2g[c] + l2b[c]) * w2wv[c];
            w = 1.f / (1.f + expf(-z));
        }
        // ---- phase 2: gather-accumulate (CSR order preserved) ----
        int u = 0;
        for (; u + 8 <= cnt; u += 8) {
            int si[8];
            float wi[8];
#pragma unroll
            for (int uu = 0; uu < 8; ++uu) {
                si[uu] = __shfl(s, u + uu, 64);
                wi[uu] = __shfl(w, u + uu, 64);
            }
            f16x4 v[8];
#pragma unroll
            for (int uu = 0; uu < 8; ++uu)
                v[uu] = *(const f16x4*)&m[(size_t)si[uu] * CDIM + lane * 4];
#pragma unroll
            for (int uu = 0; uu < 8; ++uu) {
                a0 = fmaf(wi[uu], (float)v[uu][0], a0);
                a1 = fmaf(wi[uu], (float)v[uu][1], a1);
                a2 = fmaf(wi[uu], (float)v[uu][2], a2);
                a3 = fmaf(wi[uu], (float)v[uu][3], a3);
            }
        }
        for (; u < cnt; ++u) {
            int si = __shfl(s, u, 64);
            float wi = __shfl(w, u, 64);
            f16x4 v = *(const f16x4*)&m[(size_t)si * CDIM + lane * 4];
            a0 = fmaf(wi, (float)v[0], a0);
            a1 = fmaf(wi, (float)v[1], a1);
            a2 = fmaf(wi, (float)v[2], a2);
            a3 = fmaf(wi, (float)v[3], a3);
        }
    }
    f16x4 o;
    o[0] = (_Float16)a0; o[1] = (_Float16)a1; o[2] = (_Float16)a2; o[3] = (_Float16)a3;
    *(f16x4*)&agg[(size_t)n * CDIM + lane * 4] = o;
}

__global__ __launch_bounds__(256)
void final_head_kernel(const float* __restrict__ sdot, const int* __restrict__ gstart,
                       const float* __restrict__ head_b, float* __restrict__ out) {
    int g = blockIdx.x;
    int t = threadIdx.x;
    int beg = gstart[g], end = gstart[g + 1];
    float s = 0.f;
    for (int i = beg + t; i < end; i += 256) s += sdot[i];
    __shared__ float red[256];
    red[t] = s;
    __syncthreads();
    for (int k = 128; k > 0; k >>= 1) {
        if (t < k) red[t] += red[t + k];
        __syncthreads();
    }
    if (t == 0) out[g] = red[0] / fmaxf((float)(end - beg), 1.f) + head_b[0];
}

extern "C" void kernel_launch(void* const* d_in, const int* in_sizes, int n_in,
                              void* d_out, int out_size, void* d_ws, size_t ws_size,
                              hipStream_t stream) {
    const float* x       = (const float*)d_in[0];
    const float* x_pos   = (const float*)d_in[1];
    const int*   ei      = (const int*)d_in[2];
    const int*   batch   = (const int*)d_in[3];
    const float* dense_w = (const float*)d_in[4];
    const float* dense_b = (const float*)d_in[5];
    const float* d1_w    = (const float*)d_in[6];
    const float* d1_b    = (const float*)d_in[7];
    const float* ln1_g   = (const float*)d_in[8];
    const float* ln1_b   = (const float*)d_in[9];
    const float* w1_w    = (const float*)d_in[10];
    const float* w1_b    = (const float*)d_in[11];
    const float* ln2_g   = (const float*)d_in[12];
    const float* ln2_b   = (const float*)d_in[13];
    const float* w2_w    = (const float*)d_in[14];
    const float* w2_b    = (const float*)d_in[15];
    const float* d2_w    = (const float*)d_in[16];
    const float* d2_b    = (const float*)d_in[17];
    const float* head_w  = (const float*)d_in[18];
    const float* head_b  = (const float*)d_in[19];
    float* out = (float*)d_out;

    _Float16* hbuf0 = (_Float16*)d_ws;                          // [N][256] fp16
    _Float16* hbuf1 = hbuf0 + (size_t)N_NODES * CDIM;           // [N][256] fp16
    _Float16* wt_dense = hbuf1 + (size_t)N_NODES * CDIM;        // [256][768] fp16
    _Float16* wt_sq    = wt_dense + (size_t)256 * KPAD_DENSE;   // [8][256][256] fp16
    _Float16* x_h      = wt_sq + (size_t)8 * 256 * 256;         // [N][768] fp16
    float* cw    = (float*)(x_h + (size_t)N_NODES * KPAD_DENSE);// [L][518][4]
    float* SgSb  = cw + (size_t)NLAYERS * ED_DIM * 4;           // [L][8]
    float* ns    = SgSb + NLAYERS * 8;                          // [N][12]
    float* nsp   = ns + (size_t)N_NODES * 12;                   // [4][N][12]
    float* sdot  = nsp + (size_t)4 * N_NODES * 12;              // [N]
    int* gstart    = (int*)(sdot + N_NODES);                    // [33]
    int* deg       = gstart + N_GRAPHS + 1;                     // [N]
    int* row_start = deg + N_NODES;                             // [N+1]
    int* cursor    = row_start + N_NODES + 1;                   // [N]
    int* csr_src   = cursor + N_NODES;                          // [E]
    int* bsum      = csr_src + N_EDGES;                         // [SCAN_BLOCKS]
    int* boff      = bsum + SCAN_BLOCKS;                        // [SCAN_BLOCKS]

    prep_all<<<2914, 256, 0, stream>>>(ln1_g, ln1_b, w1_w, cw, SgSb,
                                       dense_w, wt_dense, d1_w, d2_w, wt_sq, deg,
                                       sdot, x, x_h);

    hist_gstart_kernel<<<(N_EDGES + 255) / 256, 256, 0, stream>>>(ei, batch, deg, gstart);
    scan1_kernel<<<SCAN_BLOCKS, 256, 0, stream>>>(deg, bsum);
    scan2_kernel<<<1, 128, 0, stream>>>(bsum, boff);
    scan3_kernel<<<SCAN_BLOCKS, 256, 0, stream>>>(deg, boff, row_start, cursor);
    scatter_kernel<<<(N_EDGES + 255) / 256, 256, 0, stream>>>(ei, cursor, csr_src);

    const dim3 G2((N_NODES + 63) / 64, 2);  // (313, 2) = 626 blocks
    gemm_v6<12, 3, false, false, false><<<G2, 256, 0, stream>>>(
        x_h, wt_dense, dense_b, hbuf0, nullptr, nullptr, nullptr, nullptr);

    _Float16* h = hbuf0;
    _Float16* other = hbuf1;
    for (int l = 0; l < NLAYERS; l++) {
        // d1 GEMM with fused summary partials (atomic-free)
        gemm_v6<4, 2, true, false, true><<<G2, 256, 0, stream>>>(
            h, wt_sq + (size_t)l * 65536, d1_b + l * CDIM, other, nullptr, nullptr,
            cw + (size_t)l * ED_DIM * 4, nsp);
        combine_ns_kernel<<<(N_NODES * 3 + 255) / 256, 256, 0, stream>>>(nsp, ns);
        edge_agg_kernel<<<(N_NODES + 3) / 4, 256, 0, stream>>>(
            other, csr_src, row_start, ns, x_pos, cw + (size_t)l * ED_DIM * 4,
            SgSb + l * 8, w1_b + l * 4, ln2_g + l * 4, ln2_b + l * 4,
            w2_w + l * 4, w2_b + l, h);
        if (l < NLAYERS - 1) {
            gemm_v6<4, 2, true, false, false><<<G2, 256, 0, stream>>>(
                h, wt_sq + (size_t)(4 + l) * 65536, d2_b + l * CDIM, other, nullptr, nullptr,
                nullptr, nullptr);
        } else {
            // final layer: fuse node_dot into the epilogue, skip C-write
            gemm_v6<4, 2, true, true, false><<<G2, 256, 0, stream>>>(
                h, wt_sq + (size_t)(4 + l) * 65536, d2_b + l * CDIM, other, head_w, sdot,
                nullptr, nullptr);
        }
        _Float16* tmp = h; h = other; other = tmp;
    }

    final_head_kernel<<<N_GRAPHS, 256, 0, stream>>>(sdot, gstart, head_b, out);
}